// Round 6
// baseline (554.776 us; speedup 1.0000x reference)
//
#include <hip/hip_runtime.h>
#include <hip/hip_bf16.h>

typedef __attribute__((ext_vector_type(8))) short short8;      // 8 bf16 MFMA operand
typedef __attribute__((ext_vector_type(4))) float f32x4;
typedef __attribute__((ext_vector_type(4))) unsigned short u16x4;

// LDS: one 72 KB region. Phase 1-2: X stage [144 rows][512 B] swizzled bf16.
// Phase 3+: partials [8][25][16] f32 (12800 B) + alphas [25][16] f32 (1600 B)
// ALIASED onto the stage region (post-GEMM __syncthreads() orders reuse).
#define STAGE_BYTES (144 * 512)                    // 73728
#define PART_OFF    0                              // [wave][edge][graph] f32
#define ALPHA_OFF   (8 * 25 * 16 * 4)              // 12800
#define LDS_BYTES   STAGE_BYTES                    // 73728 -> 2 blocks/CU (147456 <= 163840)

__device__ __forceinline__ unsigned short f2bf(float f) {
    unsigned int u = __float_as_uint(f);
    unsigned int r = (u + 0x7fffu + ((u >> 16) & 1u)) >> 16;   // RNE
    return (unsigned short)r;
}
__device__ __forceinline__ float bflo(unsigned int u) { return __uint_as_float(u << 16); }
__device__ __forceinline__ float bfhi(unsigned int u) { return __uint_as_float(u & 0xffff0000u); }

// static graph tables (compile-time foldable in unrolled loops)
constexpr int C_SRC[25] = {0,1,0,3,0,5,0,7,1,2,3,4,5,6,7,8, 0,1,2,3,4,5,6,7,8};
constexpr int C_DST[25] = {1,0,3,0,5,0,7,0,2,1,4,3,6,5,8,7, 0,1,2,3,4,5,6,7,8};
constexpr int C_NINC[9]  = {5,3,2,3,2,3,2,3,2};
constexpr int C_IOFF[9]  = {0,5,8,10,13,15,18,20,23};
constexpr int C_INCE[25] = {1,3,5,7,16, 0,9,17, 8,18, 2,11,19, 10,20, 4,13,21, 12,22, 6,15,23, 14,24};
constexpr int C_INCS[25] = {1,3,5,7,0,  0,2,1,  1,2,  0,4,3,  3,4,  0,6,5,  5,6,  0,8,7,  7,8};
// runtime-indexed copies (softmax phase) in global const memory, not scratch
__device__ const int D_NINC[9]  = {5,3,2,3,2,3,2,3,2};
__device__ const int D_IOFF[9]  = {0,5,8,10,13,15,18,20,23};
__device__ const int D_INCE[25] = {1,3,5,7,16, 0,9,17, 8,18, 2,11,19, 10,20, 4,13,21, 12,22, 6,15,23, 14,24};

// WT[n][k] = (n<256 ? W_l[k][n] : W_r[k][n-256]) as bf16 (B-fragments contiguous)
__global__ void convert_w_kernel(const float* __restrict__ Wl,
                                 const float* __restrict__ Wr,
                                 unsigned short* __restrict__ WT) {
    int n = blockIdx.x;      // 0..511
    int k = threadIdx.x;     // 0..255
    float v = (n < 256) ? Wl[k * 256 + n] : Wr[k * 256 + (n - 256)];
    WT[n * 256 + k] = f2bf(v);
}

__global__ __launch_bounds__(512, 4) void gat_fused_kernel(
        const float* __restrict__ x,
        const unsigned short* __restrict__ WT,
        const float* __restrict__ att,
        const float* __restrict__ bias,
        float* __restrict__ out) {
    __shared__ __align__(16) char smem[LDS_BYTES];
    float* partials = (float*)(smem + PART_OFF);   // [wave][edge][graph] (aliases stage)
    float* alphas   = (float*)(smem + ALPHA_OFF);  // [edge][graph]       (aliases stage)

    const int tid  = threadIdx.x;
    const int lane = tid & 63;
    const int w    = tid >> 6;        // 8 waves; wave owns cols [32w,32w+32) of L and R
    const int gl   = lane >> 4;       // row group: graphs 4*gl..4*gl+3
    const int li   = lane & 15;       // column-within-tile
    const int blk  = blockIdx.x;

    const int c0 = 32 * w + li, c1 = c0 + 16;
    const float attc0 = att[c0], attc1 = att[c1];
    const float bc0   = bias[c0], bc1 = bias[c1];

    // ---- phase 1: stage x -> LDS bf16, node-major rows (row = node*16 + g), swizzled.
    //      Two batches of 9 f32x4 to cap transient regs at 36. ----
    const float* xblk = x + (size_t)blk * 36864;
    #pragma unroll
    for (int b = 0; b < 2; ++b) {
        f32x4 xv[9];
        #pragma unroll
        for (int it = 0; it < 9; ++it)
            xv[it] = *(const f32x4*)(xblk + (b * 9 + it) * 2048 + tid * 4);
        #pragma unroll
        for (int it = 0; it < 9; ++it) {
            int f    = (b * 9 + it) * 2048 + tid * 4;
            int gr   = f >> 8;              // g*9 + node
            int c    = f & 255;
            int g    = gr / 9;
            int node = gr - g * 9;
            int srow = node * 16 + g;       // srow & 15 == g
            u16x4 pk = { f2bf(xv[it][0]), f2bf(xv[it][1]), f2bf(xv[it][2]), f2bf(xv[it][3]) };
            *(u16x4*)(smem + srow * 512 + ((2 * c) ^ (g << 4))) = pk;
        }
    }
    __syncthreads();

    const unsigned short* WL = WT + (size_t)(c0 * 256 + gl * 8);
    const unsigned short* WR = WL + 256 * 256;
    const f32x4 ZERO = {0.f, 0.f, 0.f, 0.f};

    // packed projections: [node][tile][graph-pair] (graphs 2j lo / 2j+1 hi)
    unsigned int aRb[9][2][2];
    unsigned int aLb[9][2][2];

    // ---- phase 2a: R-GEMM (all 9 nodes) -> pack bf16 ----
    {
        f32x4 aR[9][2];
        #pragma unroll
        for (int m = 0; m < 9; ++m) { aR[m][0] = ZERO; aR[m][1] = ZERO; }
        #pragma unroll
        for (int kc = 0; kc < 8; ++kc) {
            short8 br0 = *(const short8*)(WR + kc * 32);
            short8 br1 = *(const short8*)(WR + 16 * 256 + kc * 32);
            const int inner = ((kc * 64) + (gl * 16)) ^ (li << 4);
            #pragma unroll
            for (int m = 0; m < 9; ++m) {
                short8 a = *(const short8*)(smem + (m * 16 + li) * 512 + inner);
                aR[m][0] = __builtin_amdgcn_mfma_f32_16x16x32_bf16(a, br0, aR[m][0], 0, 0, 0);
                aR[m][1] = __builtin_amdgcn_mfma_f32_16x16x32_bf16(a, br1, aR[m][1], 0, 0, 0);
            }
        }
        #pragma unroll
        for (int m = 0; m < 9; ++m)
            #pragma unroll
            for (int nt = 0; nt < 2; ++nt) {
                aRb[m][nt][0] = (unsigned int)f2bf(aR[m][nt][0]) | ((unsigned int)f2bf(aR[m][nt][1]) << 16);
                aRb[m][nt][1] = (unsigned int)f2bf(aR[m][nt][2]) | ((unsigned int)f2bf(aR[m][nt][3]) << 16);
            }
    }

    // ---- phase 2b: L-GEMM split in node halves (caps f32 accum at 5 nodes = 40 regs) ----
    #pragma unroll
    for (int half = 0; half < 2; ++half) {
        const int m0 = (half == 0) ? 0 : 5;
        const int mN = (half == 0) ? 5 : 4;
        f32x4 aL[5][2];
        #pragma unroll
        for (int m = 0; m < 5; ++m) { aL[m][0] = ZERO; aL[m][1] = ZERO; }
        #pragma unroll
        for (int kc = 0; kc < 8; ++kc) {
            short8 bl0 = *(const short8*)(WL + kc * 32);
            short8 bl1 = *(const short8*)(WL + 16 * 256 + kc * 32);
            const int inner = ((kc * 64) + (gl * 16)) ^ (li << 4);
            #pragma unroll
            for (int m = 0; m < 5; ++m) {
                if (m < mN) {
                    short8 a = *(const short8*)(smem + ((m0 + m) * 16 + li) * 512 + inner);
                    aL[m][0] = __builtin_amdgcn_mfma_f32_16x16x32_bf16(a, bl0, aL[m][0], 0, 0, 0);
                    aL[m][1] = __builtin_amdgcn_mfma_f32_16x16x32_bf16(a, bl1, aL[m][1], 0, 0, 0);
                }
            }
        }
        #pragma unroll
        for (int m = 0; m < 5; ++m) {
            if (m < mN) {
                #pragma unroll
                for (int nt = 0; nt < 2; ++nt) {
                    aLb[m0 + m][nt][0] = (unsigned int)f2bf(aL[m][nt][0]) | ((unsigned int)f2bf(aL[m][nt][1]) << 16);
                    aLb[m0 + m][nt][1] = (unsigned int)f2bf(aL[m][nt][2]) | ((unsigned int)f2bf(aL[m][nt][3]) << 16);
                }
            }
        }
    }
    __syncthreads();   // all stage-region reads done; region becomes partials/alphas

    // ---- phase 3: per-edge scores from packed bf16 + 16-lane butterfly ----
    #pragma unroll
    for (int e = 0; e < 25; ++e) {
        const int s = C_SRC[e], d = C_DST[e];
        float p0 = 0.f, p1 = 0.f, p2 = 0.f, p3 = 0.f;
        #pragma unroll
        for (int nt = 0; nt < 2; ++nt) {
            const float ac = nt ? attc1 : attc0;
            float v0 = bflo(aLb[s][nt][0]) + bflo(aRb[d][nt][0]);
            float v1 = bfhi(aLb[s][nt][0]) + bfhi(aRb[d][nt][0]);
            float v2 = bflo(aLb[s][nt][1]) + bflo(aRb[d][nt][1]);
            float v3 = bfhi(aLb[s][nt][1]) + bfhi(aRb[d][nt][1]);
            p0 += ac * fmaxf(v0, 0.2f * v0);
            p1 += ac * fmaxf(v1, 0.2f * v1);
            p2 += ac * fmaxf(v2, 0.2f * v2);
            p3 += ac * fmaxf(v3, 0.2f * v3);
        }
        #pragma unroll
        for (int m = 1; m < 16; m <<= 1) {              // sum over the 16 cols of this wave
            p0 += __shfl_xor(p0, m);
            p1 += __shfl_xor(p1, m);
            p2 += __shfl_xor(p2, m);
            p3 += __shfl_xor(p3, m);
        }
        if (li == 0) {
            f32x4 pk = {p0, p1, p2, p3};
            *(f32x4*)(partials + (w * 25 + e) * 16 + 4 * gl) = pk;
        }
    }
    __syncthreads();

    // ---- phase 4: segment softmax, one thread per (node, graph) ----
    if (tid < 144) {
        int n = tid >> 4, g = tid & 15;
        int off = D_IOFF[n], cnt = D_NINC[n];
        float mx = -1e30f;
        for (int i = 0; i < cnt; ++i) {
            int e = D_INCE[off + i];
            float s = 0.f;
            #pragma unroll
            for (int ww = 0; ww < 8; ++ww) s += partials[(ww * 25 + e) * 16 + g];
            alphas[e * 16 + g] = s;                     // scratch: raw score
            mx = fmaxf(mx, s);
        }
        float ssum = 0.f;
        for (int i = 0; i < cnt; ++i)
            ssum += __expf(alphas[D_INCE[off + i] * 16 + g] - mx);
        float inv = 1.f / ssum;
        for (int i = 0; i < cnt; ++i) {
            int e = D_INCE[off + i];
            alphas[e * 16 + g] = __expf(alphas[e * 16 + g] - mx) * inv;
        }
    }
    __syncthreads();

    // ---- phase 5: aggregate from packed bf16 (alpha tile-diagonal in node-major order) ----
    #pragma unroll
    for (int n = 0; n < 9; ++n) {
        f32x4 o0 = {bc0, bc0, bc0, bc0};
        f32x4 o1 = {bc1, bc1, bc1, bc1};
        #pragma unroll
        for (int i = 0; i < C_NINC[n]; ++i) {
            const int e  = C_INCE[C_IOFF[n] + i];
            const int sn = C_INCS[C_IOFF[n] + i];
            f32x4 al = *(const f32x4*)(alphas + e * 16 + 4 * gl);   // alpha for graphs 4gl..4gl+3
            o0[0] += al[0] * bflo(aLb[sn][0][0]);
            o0[1] += al[1] * bfhi(aLb[sn][0][0]);
            o0[2] += al[2] * bflo(aLb[sn][0][1]);
            o0[3] += al[3] * bfhi(aLb[sn][0][1]);
            o1[0] += al[0] * bflo(aLb[sn][1][0]);
            o1[1] += al[1] * bfhi(aLb[sn][1][0]);
            o1[2] += al[2] * bflo(aLb[sn][1][1]);
            o1[3] += al[3] * bfhi(aLb[sn][1][1]);
        }
        #pragma unroll
        for (int r = 0; r < 4; ++r) {
            size_t row = (size_t)(blk * 16 + 4 * gl + r) * 9 + n;
            out[row * 256 + c0] = o0[r];
            out[row * 256 + c1] = o1[r];
        }
    }
}

extern "C" void kernel_launch(void* const* d_in, const int* in_sizes, int n_in,
                              void* d_out, int out_size, void* d_ws, size_t ws_size,
                              hipStream_t stream) {
    const float* x    = (const float*)d_in[0];
    const float* Wl   = (const float*)d_in[1];
    const float* Wr   = (const float*)d_in[2];
    const float* att  = (const float*)d_in[3];
    const float* bias = (const float*)d_in[4];
    float* out = (float*)d_out;
    unsigned short* WT = (unsigned short*)d_ws;      // 512*256 bf16 = 256 KB

    convert_w_kernel<<<512, 256, 0, stream>>>(Wl, Wr, WT);
    gat_fused_kernel<<<1024, 512, 0, stream>>>(x, WT, att, bias, out);
}

// Round 7
// 365.678 us; speedup vs baseline: 1.5171x; 1.5171x over previous
//
#include <hip/hip_runtime.h>
#include <hip/hip_bf16.h>

typedef __attribute__((ext_vector_type(8))) short short8;      // 8 bf16 MFMA operand
typedef __attribute__((ext_vector_type(4))) float f32x4;
typedef __attribute__((ext_vector_type(4))) unsigned short u16x4;

// Persistent kernel: 256 blocks (1/CU), NU=4 graph-units each.
// LDS: two 72KB stage buffers (double-buffered) + partials + alphas (separate).
#define STAGE_BYTES (144 * 512)                    // 73728 per buffer
#define NU 4
#define PART_OFF  (2 * STAGE_BYTES)                // 147456: [8][25][16] f32
#define ALPHA_OFF (PART_OFF + 8 * 25 * 16 * 4)     // 160256: [25][16] f32
#define LDS_BYTES (ALPHA_OFF + 25 * 16 * 4)        // 161856 <= 163840

__device__ __forceinline__ unsigned short f2bf(float f) {
    unsigned int u = __float_as_uint(f);
    unsigned int r = (u + 0x7fffu + ((u >> 16) & 1u)) >> 16;   // RNE
    return (unsigned short)r;
}

// static graph tables (compile-time foldable in unrolled loops)
constexpr int C_SRC[25] = {0,1,0,3,0,5,0,7,1,2,3,4,5,6,7,8, 0,1,2,3,4,5,6,7,8};
constexpr int C_DST[25] = {1,0,3,0,5,0,7,0,2,1,4,3,6,5,8,7, 0,1,2,3,4,5,6,7,8};
constexpr int C_NINC[9]  = {5,3,2,3,2,3,2,3,2};
constexpr int C_IOFF[9]  = {0,5,8,10,13,15,18,20,23};
constexpr int C_INCE[25] = {1,3,5,7,16, 0,9,17, 8,18, 2,11,19, 10,20, 4,13,21, 12,22, 6,15,23, 14,24};
constexpr int C_INCS[25] = {1,3,5,7,0,  0,2,1,  1,2,  0,4,3,  3,4,  0,6,5,  5,6,  0,8,7,  7,8};
// runtime-indexed copies (softmax phase) in global const memory, not scratch
__device__ const int D_NINC[9]  = {5,3,2,3,2,3,2,3,2};
__device__ const int D_IOFF[9]  = {0,5,8,10,13,15,18,20,23};
__device__ const int D_INCE[25] = {1,3,5,7,16, 0,9,17, 8,18, 2,11,19, 10,20, 4,13,21, 12,22, 6,15,23, 14,24};

// WT[n][k] = (n<256 ? W_l[k][n] : W_r[k][n-256]) as bf16 (B-fragments contiguous)
__global__ void convert_w_kernel(const float* __restrict__ Wl,
                                 const float* __restrict__ Wr,
                                 unsigned short* __restrict__ WT) {
    int n = blockIdx.x;      // 0..511
    int k = threadIdx.x;     // 0..255
    float v = (n < 256) ? Wl[k * 256 + n] : Wr[k * 256 + (n - 256)];
    WT[n * 256 + k] = f2bf(v);
}

__global__ __launch_bounds__(512, 2) void gat_fused_kernel(
        const float* __restrict__ x,
        const unsigned short* __restrict__ WT,
        const float* __restrict__ att,
        const float* __restrict__ bias,
        float* __restrict__ out) {
    __shared__ __align__(16) char smem[LDS_BYTES];
    float* partials = (float*)(smem + PART_OFF);   // [wave][edge][graph]
    float* alphas   = (float*)(smem + ALPHA_OFF);  // [edge][graph]

    const int tid  = threadIdx.x;
    const int lane = tid & 63;
    const int w    = tid >> 6;        // 8 waves; wave owns cols [32w,32w+32) of L and R
    const int gl   = lane >> 4;       // row group: graphs 4*gl..4*gl+3
    const int li   = lane & 15;       // column-within-tile
    const int c0 = 32 * w + li, c1 = c0 + 16;
    const float attc0 = att[c0], attc1 = att[c1];
    const float bc0   = bias[c0], bc1 = bias[c1];

    // staging helper: write one 9-load batch to a buffer (node-major swizzled bf16)
    auto stage_batch = [&](char* dst, const f32x4* xv, int b) {
        #pragma unroll
        for (int it = 0; it < 9; ++it) {
            int f    = (b * 9 + it) * 2048 + tid * 4;
            int gr   = f >> 8;              // g*9 + node
            int c    = f & 255;
            int g    = gr / 9;
            int node = gr - g * 9;
            int srow = node * 16 + g;       // srow & 15 == g
            u16x4 pk = { f2bf(xv[it][0]), f2bf(xv[it][1]), f2bf(xv[it][2]), f2bf(xv[it][3]) };
            *(u16x4*)(dst + srow * 512 + ((2 * c) ^ (g << 4))) = pk;
        }
    };

    const unsigned short* WL = WT + (size_t)(c0 * 256 + gl * 8);
    const unsigned short* WR = WL + 256 * 256;
    const f32x4 ZERO = {0.f, 0.f, 0.f, 0.f};

    // ---- prologue: stage unit 0 into buffer 0 ----
    {
        const float* xblk = x + (size_t)(blockIdx.x * NU) * 36864;
        #pragma unroll
        for (int b = 0; b < 2; ++b) {
            f32x4 xv[9];
            #pragma unroll
            for (int it = 0; it < 9; ++it)
                xv[it] = *(const f32x4*)(xblk + (b * 9 + it) * 2048 + tid * 4);
            stage_batch(smem, xv, b);
        }
    }
    __syncthreads();

    int cur = 0;
    for (int u = 0; u < NU; ++u) {
        char* bufc = smem + cur * STAGE_BYTES;
        char* bufn = smem + (cur ^ 1) * STAGE_BYTES;
        const bool more = (u + 1 < NU);
        const float* xnext = x + (size_t)(blockIdx.x * NU + u + 1) * 36864;

        // ---- GEMM on current buffer -> registers ----
        f32x4 aL[9][2], aR[9][2];
        #pragma unroll
        for (int m = 0; m < 9; ++m) {
            aL[m][0] = ZERO; aL[m][1] = ZERO; aR[m][0] = ZERO; aR[m][1] = ZERO;
        }
        #pragma unroll
        for (int kc = 0; kc < 8; ++kc) {
            short8 bl0 = *(const short8*)(WL + kc * 32);
            short8 bl1 = *(const short8*)(WL + 16 * 256 + kc * 32);
            short8 br0 = *(const short8*)(WR + kc * 32);
            short8 br1 = *(const short8*)(WR + 16 * 256 + kc * 32);
            const int inner = ((kc * 64) + (gl * 16)) ^ (li << 4);
            short8 am[9];
            #pragma unroll
            for (int m = 0; m < 9; ++m)
                am[m] = *(const short8*)(bufc + (m * 16 + li) * 512 + inner);
            #pragma unroll
            for (int m = 0; m < 9; ++m) {
                aL[m][0] = __builtin_amdgcn_mfma_f32_16x16x32_bf16(am[m], bl0, aL[m][0], 0, 0, 0);
                aL[m][1] = __builtin_amdgcn_mfma_f32_16x16x32_bf16(am[m], bl1, aL[m][1], 0, 0, 0);
                aR[m][0] = __builtin_amdgcn_mfma_f32_16x16x32_bf16(am[m], br0, aR[m][0], 0, 0, 0);
                aR[m][1] = __builtin_amdgcn_mfma_f32_16x16x32_bf16(am[m], br1, aR[m][1], 0, 0, 0);
            }
        }
        // D-frag: col = li (within tile), row = 4*gl + r = graph.

        // ---- prefetch batch 0 of next unit (loads only; writes after barrier) ----
        f32x4 xv0[9];
        if (more) {
            #pragma unroll
            for (int it = 0; it < 9; ++it)
                xv0[it] = *(const f32x4*)(xnext + it * 2048 + tid * 4);
        }
        __builtin_amdgcn_sched_barrier(0);   // pin load issue here (don't sink past phase 3)

        // ---- phase 3: per-edge scores, registers + 16-lane butterfly ----
        #pragma unroll
        for (int e = 0; e < 25; ++e) {
            const int s = C_SRC[e], d = C_DST[e];
            float p0 = 0.f, p1 = 0.f, p2 = 0.f, p3 = 0.f;
            #pragma unroll
            for (int nt = 0; nt < 2; ++nt) {
                const float ac = nt ? attc1 : attc0;
                #pragma unroll
                for (int r = 0; r < 4; ++r) {
                    float v  = aL[s][nt][r] + aR[d][nt][r];
                    float lr = fmaxf(v, 0.2f * v);          // LeakyReLU(0.2)
                    float t  = ac * lr;
                    if (r == 0) p0 += t; else if (r == 1) p1 += t;
                    else if (r == 2) p2 += t; else p3 += t;
                }
            }
            #pragma unroll
            for (int m = 1; m < 16; m <<= 1) {
                p0 += __shfl_xor(p0, m);
                p1 += __shfl_xor(p1, m);
                p2 += __shfl_xor(p2, m);
                p3 += __shfl_xor(p3, m);
            }
            if (li == 0) {
                f32x4 pk = {p0, p1, p2, p3};
                *(f32x4*)(partials + (w * 25 + e) * 16 + 4 * gl) = pk;
            }
        }
        __syncthreads();   // (a) partials ready

        // ---- write batch 0 to next buffer; issue batch 1 ----
        f32x4 xv1[9];
        if (more) {
            stage_batch(bufn, xv0, 0);
            #pragma unroll
            for (int it = 0; it < 9; ++it)
                xv1[it] = *(const f32x4*)(xnext + (9 + it) * 2048 + tid * 4);
        }
        __builtin_amdgcn_sched_barrier(0);

        // ---- phase 4: segment softmax, one thread per (node, graph) ----
        if (tid < 144) {
            int n = tid >> 4, g = tid & 15;
            int off = D_IOFF[n], cnt = D_NINC[n];
            float mx = -1e30f;
            for (int i = 0; i < cnt; ++i) {
                int e = D_INCE[off + i];
                float s = 0.f;
                #pragma unroll
                for (int ww = 0; ww < 8; ++ww) s += partials[(ww * 25 + e) * 16 + g];
                alphas[e * 16 + g] = s;                     // scratch: raw score
                mx = fmaxf(mx, s);
            }
            float ssum = 0.f;
            for (int i = 0; i < cnt; ++i)
                ssum += __expf(alphas[D_INCE[off + i] * 16 + g] - mx);
            float inv = 1.f / ssum;
            for (int i = 0; i < cnt; ++i) {
                int e = D_INCE[off + i];
                alphas[e * 16 + g] = __expf(alphas[e * 16 + g] - mx) * inv;
            }
        }
        __syncthreads();   // (b) alphas ready

        // ---- write batch 1 to next buffer ----
        if (more) stage_batch(bufn, xv1, 1);

        // ---- phase 5: aggregate in registers, store out ----
        float* outblk = out + (size_t)(blockIdx.x * NU + u) * 36864;
        #pragma unroll
        for (int n = 0; n < 9; ++n) {
            f32x4 o0 = {bc0, bc0, bc0, bc0};
            f32x4 o1 = {bc1, bc1, bc1, bc1};
            #pragma unroll
            for (int i = 0; i < C_NINC[n]; ++i) {
                const int e  = C_INCE[C_IOFF[n] + i];
                const int sn = C_INCS[C_IOFF[n] + i];
                f32x4 al = *(const f32x4*)(alphas + e * 16 + 4 * gl);
                #pragma unroll
                for (int r = 0; r < 4; ++r) {
                    o0[r] += al[r] * aL[sn][0][r];
                    o1[r] += al[r] * aL[sn][1][r];
                }
            }
            #pragma unroll
            for (int r = 0; r < 4; ++r) {
                int row = (4 * gl + r) * 9 + n;
                outblk[row * 256 + c0] = o0[r];
                outblk[row * 256 + c1] = o1[r];
            }
        }
        __syncthreads();   // (c) alphas/partials reusable; bufn writes complete
        cur ^= 1;
    }
}

extern "C" void kernel_launch(void* const* d_in, const int* in_sizes, int n_in,
                              void* d_out, int out_size, void* d_ws, size_t ws_size,
                              hipStream_t stream) {
    const float* x    = (const float*)d_in[0];
    const float* Wl   = (const float*)d_in[1];
    const float* Wr   = (const float*)d_in[2];
    const float* att  = (const float*)d_in[3];
    const float* bias = (const float*)d_in[4];
    float* out = (float*)d_out;
    unsigned short* WT = (unsigned short*)d_ws;      // 512*256 bf16 = 256 KB

    convert_w_kernel<<<512, 256, 0, stream>>>(Wl, Wr, WT);
    gat_fused_kernel<<<256, 512, 0, stream>>>(x, WT, att, bias, out);
}

// Round 8
// 337.564 us; speedup vs baseline: 1.6435x; 1.0833x over previous
//
#include <hip/hip_runtime.h>
#include <hip/hip_bf16.h>

typedef __attribute__((ext_vector_type(8))) short short8;      // 8 bf16 MFMA operand
typedef __attribute__((ext_vector_type(4))) float f32x4;
typedef __attribute__((ext_vector_type(4))) unsigned short u16x4;

// ---------------- shared constants ----------------
#define STAGE_BYTES 73728                          // 144 rows x 512 B (bf16, swizzled)
#define NU 4                                       // units per persistent block
// main-kernel LDS: two stage buffers + partials + alphas
#define PART_OFF  (2 * STAGE_BYTES)                // 147456: [8][25][16] f32
#define ALPHA_OFF (PART_OFF + 8 * 25 * 16 * 4)     // 160256: [25][16] f32
#define MAIN_LDS  (ALPHA_OFF + 25 * 16 * 4)        // 161856 <= 163840

#define WT_BYTES   (512 * 256 * 2)                 // 262144
#define XPRE_BYTES (1024 * STAGE_BYTES)            // 75497472
#define WS_NEED    ((size_t)WT_BYTES + (size_t)XPRE_BYTES)

__device__ __forceinline__ unsigned short f2bf(float f) {
    unsigned int u = __float_as_uint(f);
    unsigned int r = (u + 0x7fffu + ((u >> 16) & 1u)) >> 16;   // RNE
    return (unsigned short)r;
}

__device__ __forceinline__ void gload_lds16(const unsigned char* g, unsigned char* l) {
    // async global->LDS, 16 B per lane; LDS dest = wave-uniform base + lane*16
    __builtin_amdgcn_global_load_lds(
        (const __attribute__((address_space(1))) unsigned int*)g,
        (__attribute__((address_space(3))) unsigned int*)l,
        16, 0, 0);
}

// static graph tables
constexpr int C_SRC[25] = {0,1,0,3,0,5,0,7,1,2,3,4,5,6,7,8, 0,1,2,3,4,5,6,7,8};
constexpr int C_DST[25] = {1,0,3,0,5,0,7,0,2,1,4,3,6,5,8,7, 0,1,2,3,4,5,6,7,8};
constexpr int C_NINC[9]  = {5,3,2,3,2,3,2,3,2};
constexpr int C_IOFF[9]  = {0,5,8,10,13,15,18,20,23};
constexpr int C_INCE[25] = {1,3,5,7,16, 0,9,17, 8,18, 2,11,19, 10,20, 4,13,21, 12,22, 6,15,23, 14,24};
constexpr int C_INCS[25] = {1,3,5,7,0,  0,2,1,  1,2,  0,4,3,  3,4,  0,6,5,  5,6,  0,8,7,  7,8};
__device__ const int D_NINC[9]  = {5,3,2,3,2,3,2,3,2};
__device__ const int D_IOFF[9]  = {0,5,8,10,13,15,18,20,23};
__device__ const int D_INCE[25] = {1,3,5,7,16, 0,9,17, 8,18, 2,11,19, 10,20, 4,13,21, 12,22, 6,15,23, 14,24};

// WT[n][k] = (n<256 ? W_l[k][n] : W_r[k][n-256]) as bf16 (B-fragments contiguous)
__global__ void convert_w_kernel(const float* __restrict__ Wl,
                                 const float* __restrict__ Wr,
                                 unsigned short* __restrict__ WT) {
    int n = blockIdx.x;      // 0..511
    int k = threadIdx.x;     // 0..255
    float v = (n < 256) ? Wl[k * 256 + n] : Wr[k * 256 + (n - 256)];
    WT[n * 256 + k] = f2bf(v);
}

// x (f32, [B,9,256]) -> x_pre (bf16, unit-blocked LDS stage image):
// unit u byte i: srow = i>>9 (node*16+g), inner = i&511 = (2c)^(g<<4)
__global__ __launch_bounds__(512) void cvt_x_kernel(const float* __restrict__ x,
                                                    unsigned char* __restrict__ xp) {
    const int u = blockIdx.x;                     // 0..1023
    const int t = threadIdx.x;                    // 0..511
    const float* xu = x + (size_t)u * 36864;
    unsigned char* xpu = xp + (size_t)u * STAGE_BYTES;
    #pragma unroll
    for (int it = 0; it < 9; ++it) {
        int ci   = it * 512 + t;                  // 16B-chunk index, 0..4607
        int srow = ci >> 5;
        int g    = srow & 15, node = srow >> 4;
        int ib   = (ci & 31) * 16;
        int cb   = (ib ^ (g << 4)) >> 1;          // first of 8 consecutive cols
        const float* src = xu + ((size_t)g * 9 + node) * 256 + cb;
        f32x4 a = *(const f32x4*)(src);
        f32x4 b = *(const f32x4*)(src + 4);
        u16x4 lo = { f2bf(a[0]), f2bf(a[1]), f2bf(a[2]), f2bf(a[3]) };
        u16x4 hi = { f2bf(b[0]), f2bf(b[1]), f2bf(b[2]), f2bf(b[3]) };
        *(u16x4*)(xpu + ci * 16)     = lo;
        *(u16x4*)(xpu + ci * 16 + 8) = hi;
    }
}

// persistent fused kernel: 256 blocks, NU units each, double-buffered via global_load_lds
__global__ __launch_bounds__(512, 2) void gat_main_kernel(
        const unsigned char* __restrict__ xp,
        const unsigned short* __restrict__ WT,
        const float* __restrict__ att,
        const float* __restrict__ bias,
        float* __restrict__ out) {
    __shared__ __align__(16) unsigned char smem[MAIN_LDS];
    float* partials = (float*)(smem + PART_OFF);
    float* alphas   = (float*)(smem + ALPHA_OFF);

    const int tid  = threadIdx.x;
    const int lane = tid & 63;
    const int w    = tid >> 6;        // 8 waves; wave owns cols [32w,32w+32) of L and R
    const int gl   = lane >> 4;       // graphs 4*gl..4*gl+3
    const int li   = lane & 15;
    const int c0 = 32 * w + li, c1 = c0 + 16;
    const float attc0 = att[c0], attc1 = att[c1];
    const float bc0   = bias[c0], bc1 = bias[c1];

    const unsigned short* WL = WT + (size_t)(c0 * 256 + gl * 8);
    const unsigned short* WR = WL + 256 * 256;
    const f32x4 ZERO = {0.f, 0.f, 0.f, 0.f};
    const size_t unit0 = (size_t)blockIdx.x * NU;

    // prologue: DMA unit 0 into buf0 (9 x 16B per thread, zero VGPR payload)
    {
        const unsigned char* src = xp + unit0 * STAGE_BYTES;
        #pragma unroll
        for (int j = 0; j < 9; ++j)
            gload_lds16(src + ((w * 9 + j) << 10) + lane * 16, smem + ((w * 9 + j) << 10));
    }
    __syncthreads();   // vmcnt drain + barrier: buf0 ready

    int cur = 0;
    for (int u = 0; u < NU; ++u) {
        unsigned char* bufc = smem + cur * STAGE_BYTES;
        unsigned char* bufn = smem + (cur ^ 1) * STAGE_BYTES;

        // ---- issue next unit's DMA into bufn (reads of bufn ended before barrier (a,u-1)) ----
        if (u + 1 < NU) {
            const unsigned char* src = xp + (unit0 + u + 1) * STAGE_BYTES;
            #pragma unroll
            for (int j = 0; j < 9; ++j)
                gload_lds16(src + ((w * 9 + j) << 10) + lane * 16, bufn + ((w * 9 + j) << 10));
        }

        // ---- GEMM on current buffer -> registers ----
        f32x4 aL[9][2], aR[9][2];
        #pragma unroll
        for (int m = 0; m < 9; ++m) {
            aL[m][0] = ZERO; aL[m][1] = ZERO; aR[m][0] = ZERO; aR[m][1] = ZERO;
        }
        #pragma unroll
        for (int kc = 0; kc < 8; ++kc) {
            short8 bl0 = *(const short8*)(WL + kc * 32);
            short8 bl1 = *(const short8*)(WL + 16 * 256 + kc * 32);
            short8 br0 = *(const short8*)(WR + kc * 32);
            short8 br1 = *(const short8*)(WR + 16 * 256 + kc * 32);
            const int inner = ((kc * 64) + (gl * 16)) ^ (li << 4);
            short8 am[9];
            #pragma unroll
            for (int m = 0; m < 9; ++m)
                am[m] = *(const short8*)(bufc + (m * 16 + li) * 512 + inner);
            #pragma unroll
            for (int m = 0; m < 9; ++m) {
                aL[m][0] = __builtin_amdgcn_mfma_f32_16x16x32_bf16(am[m], bl0, aL[m][0], 0, 0, 0);
                aL[m][1] = __builtin_amdgcn_mfma_f32_16x16x32_bf16(am[m], bl1, aL[m][1], 0, 0, 0);
                aR[m][0] = __builtin_amdgcn_mfma_f32_16x16x32_bf16(am[m], br0, aR[m][0], 0, 0, 0);
                aR[m][1] = __builtin_amdgcn_mfma_f32_16x16x32_bf16(am[m], br1, aR[m][1], 0, 0, 0);
            }
        }
        // D-frag: col = li (within tile), row = 4*gl + r = graph.

        // ---- per-edge scores, registers + 16-lane butterfly ----
        #pragma unroll
        for (int e = 0; e < 25; ++e) {
            const int s = C_SRC[e], d = C_DST[e];
            float p0 = 0.f, p1 = 0.f, p2 = 0.f, p3 = 0.f;
            #pragma unroll
            for (int nt = 0; nt < 2; ++nt) {
                const float ac = nt ? attc1 : attc0;
                #pragma unroll
                for (int r = 0; r < 4; ++r) {
                    float v  = aL[s][nt][r] + aR[d][nt][r];
                    float lr = fmaxf(v, 0.2f * v);          // LeakyReLU(0.2)
                    float t  = ac * lr;
                    if (r == 0) p0 += t; else if (r == 1) p1 += t;
                    else if (r == 2) p2 += t; else p3 += t;
                }
            }
            #pragma unroll
            for (int m = 1; m < 16; m <<= 1) {
                p0 += __shfl_xor(p0, m);
                p1 += __shfl_xor(p1, m);
                p2 += __shfl_xor(p2, m);
                p3 += __shfl_xor(p3, m);
            }
            if (li == 0) {
                f32x4 pk = {p0, p1, p2, p3};
                *(f32x4*)(partials + (w * 25 + e) * 16 + 4 * gl) = pk;
            }
        }
        __syncthreads();   // (a) partials ready; drains this wave's DMA for u+1

        // ---- segment softmax, one thread per (node, graph) ----
        if (tid < 144) {
            int n = tid >> 4, g = tid & 15;
            int off = D_IOFF[n], cnt = D_NINC[n];
            float mx = -1e30f;
            for (int i = 0; i < cnt; ++i) {
                int e = D_INCE[off + i];
                float s = 0.f;
                #pragma unroll
                for (int ww = 0; ww < 8; ++ww) s += partials[(ww * 25 + e) * 16 + g];
                alphas[e * 16 + g] = s;
                mx = fmaxf(mx, s);
            }
            float ssum = 0.f;
            for (int i = 0; i < cnt; ++i)
                ssum += __expf(alphas[D_INCE[off + i] * 16 + g] - mx);
            float inv = 1.f / ssum;
            for (int i = 0; i < cnt; ++i) {
                int e = D_INCE[off + i];
                alphas[e * 16 + g] = __expf(alphas[e * 16 + g] - mx) * inv;
            }
        }
        __syncthreads();   // (b) alphas ready

        // ---- aggregate in registers, store out ----
        float* outblk = out + (unit0 + u) * 36864;
        #pragma unroll
        for (int n = 0; n < 9; ++n) {
            f32x4 o0 = {bc0, bc0, bc0, bc0};
            f32x4 o1 = {bc1, bc1, bc1, bc1};
            #pragma unroll
            for (int i = 0; i < C_NINC[n]; ++i) {
                const int e  = C_INCE[C_IOFF[n] + i];
                const int sn = C_INCS[C_IOFF[n] + i];
                f32x4 al = *(const f32x4*)(alphas + e * 16 + 4 * gl);
                #pragma unroll
                for (int r = 0; r < 4; ++r) {
                    o0[r] += al[r] * aL[sn][0][r];
                    o1[r] += al[r] * aL[sn][1][r];
                }
            }
            #pragma unroll
            for (int r = 0; r < 4; ++r) {
                int row = (4 * gl + r) * 9 + n;
                outblk[row * 256 + c0] = o0[r];
                outblk[row * 256 + c1] = o1[r];
            }
        }
        cur ^= 1;
        // no end barrier needed: next iteration's DMA targets the buffer whose
        // last reads (this GEMM) completed before (a,u); partials/alphas reuse
        // is ordered by (a)/(b) of the next iteration.
    }
}

// ---------------- fallback (round-2 structure): used if ws too small ----------------
#define L_PART_OFF  0
#define L_ALPHA_OFF (8 * 25 * 16 * 4)
__global__ __launch_bounds__(512, 2) void gat_fused_legacy(
        const float* __restrict__ x,
        const unsigned short* __restrict__ WT,
        const float* __restrict__ att,
        const float* __restrict__ bias,
        float* __restrict__ out) {
    __shared__ __align__(16) char smem[STAGE_BYTES];
    float* partials = (float*)(smem + L_PART_OFF);
    float* alphas   = (float*)(smem + L_ALPHA_OFF);

    const int tid  = threadIdx.x;
    const int lane = tid & 63;
    const int w    = tid >> 6;
    const int gl   = lane >> 4;
    const int li   = lane & 15;
    const int blk  = blockIdx.x;
    const int c0 = 32 * w + li, c1 = c0 + 16;
    const float attc0 = att[c0], attc1 = att[c1];
    const float bc0   = bias[c0], bc1 = bias[c1];

    const float* xblk = x + (size_t)blk * 36864;
    {
        f32x4 xv[18];
        #pragma unroll
        for (int it = 0; it < 18; ++it)
            xv[it] = *(const f32x4*)(xblk + it * 2048 + tid * 4);
        #pragma unroll
        for (int it = 0; it < 18; ++it) {
            int f    = it * 2048 + tid * 4;
            int gr   = f >> 8;
            int c    = f & 255;
            int g    = gr / 9;
            int node = gr - g * 9;
            int srow = node * 16 + g;
            u16x4 pk = { f2bf(xv[it][0]), f2bf(xv[it][1]), f2bf(xv[it][2]), f2bf(xv[it][3]) };
            *(u16x4*)(smem + srow * 512 + ((2 * c) ^ (g << 4))) = pk;
        }
    }
    __syncthreads();

    const unsigned short* WL = WT + (size_t)(c0 * 256 + gl * 8);
    const unsigned short* WR = WL + 256 * 256;
    const f32x4 ZERO = {0.f, 0.f, 0.f, 0.f};
    f32x4 aL[9][2], aR[9][2];
    #pragma unroll
    for (int m = 0; m < 9; ++m) {
        aL[m][0] = ZERO; aL[m][1] = ZERO; aR[m][0] = ZERO; aR[m][1] = ZERO;
    }
    #pragma unroll
    for (int kc = 0; kc < 8; ++kc) {
        short8 bl0 = *(const short8*)(WL + kc * 32);
        short8 bl1 = *(const short8*)(WL + 16 * 256 + kc * 32);
        short8 br0 = *(const short8*)(WR + kc * 32);
        short8 br1 = *(const short8*)(WR + 16 * 256 + kc * 32);
        const int inner = ((kc * 64) + (gl * 16)) ^ (li << 4);
        short8 am[9];
        #pragma unroll
        for (int m = 0; m < 9; ++m)
            am[m] = *(const short8*)(smem + (m * 16 + li) * 512 + inner);
        #pragma unroll
        for (int m = 0; m < 9; ++m) {
            aL[m][0] = __builtin_amdgcn_mfma_f32_16x16x32_bf16(am[m], bl0, aL[m][0], 0, 0, 0);
            aL[m][1] = __builtin_amdgcn_mfma_f32_16x16x32_bf16(am[m], bl1, aL[m][1], 0, 0, 0);
            aR[m][0] = __builtin_amdgcn_mfma_f32_16x16x32_bf16(am[m], br0, aR[m][0], 0, 0, 0);
            aR[m][1] = __builtin_amdgcn_mfma_f32_16x16x32_bf16(am[m], br1, aR[m][1], 0, 0, 0);
        }
    }
    __syncthreads();

    #pragma unroll
    for (int e = 0; e < 25; ++e) {
        const int s = C_SRC[e], d = C_DST[e];
        float p0 = 0.f, p1 = 0.f, p2 = 0.f, p3 = 0.f;
        #pragma unroll
        for (int nt = 0; nt < 2; ++nt) {
            const float ac = nt ? attc1 : attc0;
            #pragma unroll
            for (int r = 0; r < 4; ++r) {
                float v  = aL[s][nt][r] + aR[d][nt][r];
                float lr = fmaxf(v, 0.2f * v);
                float t  = ac * lr;
                if (r == 0) p0 += t; else if (r == 1) p1 += t;
                else if (r == 2) p2 += t; else p3 += t;
            }
        }
        #pragma unroll
        for (int m = 1; m < 16; m <<= 1) {
            p0 += __shfl_xor(p0, m);
            p1 += __shfl_xor(p1, m);
            p2 += __shfl_xor(p2, m);
            p3 += __shfl_xor(p3, m);
        }
        if (li == 0) {
            f32x4 pk = {p0, p1, p2, p3};
            *(f32x4*)(partials + (w * 25 + e) * 16 + 4 * gl) = pk;
        }
    }
    __syncthreads();

    if (tid < 144) {
        int n = tid >> 4, g = tid & 15;
        int off = D_IOFF[n], cnt = D_NINC[n];
        float mx = -1e30f;
        for (int i = 0; i < cnt; ++i) {
            int e = D_INCE[off + i];
            float s = 0.f;
            #pragma unroll
            for (int ww = 0; ww < 8; ++ww) s += partials[(ww * 25 + e) * 16 + g];
            alphas[e * 16 + g] = s;
            mx = fmaxf(mx, s);
        }
        float ssum = 0.f;
        for (int i = 0; i < cnt; ++i)
            ssum += __expf(alphas[D_INCE[off + i] * 16 + g] - mx);
        float inv = 1.f / ssum;
        for (int i = 0; i < cnt; ++i) {
            int e = D_INCE[off + i];
            alphas[e * 16 + g] = __expf(alphas[e * 16 + g] - mx) * inv;
        }
    }
    __syncthreads();

    #pragma unroll
    for (int n = 0; n < 9; ++n) {
        f32x4 o0 = {bc0, bc0, bc0, bc0};
        f32x4 o1 = {bc1, bc1, bc1, bc1};
        #pragma unroll
        for (int i = 0; i < C_NINC[n]; ++i) {
            const int e  = C_INCE[C_IOFF[n] + i];
            const int sn = C_INCS[C_IOFF[n] + i];
            f32x4 al = *(const f32x4*)(alphas + e * 16 + 4 * gl);
            #pragma unroll
            for (int r = 0; r < 4; ++r) {
                o0[r] += al[r] * aL[sn][0][r];
                o1[r] += al[r] * aL[sn][1][r];
            }
        }
        #pragma unroll
        for (int r = 0; r < 4; ++r) {
            size_t row = (size_t)(blk * 16 + 4 * gl + r) * 9 + n;
            out[row * 256 + c0] = o0[r];
            out[row * 256 + c1] = o1[r];
        }
    }
}

extern "C" void kernel_launch(void* const* d_in, const int* in_sizes, int n_in,
                              void* d_out, int out_size, void* d_ws, size_t ws_size,
                              hipStream_t stream) {
    const float* x    = (const float*)d_in[0];
    const float* Wl   = (const float*)d_in[1];
    const float* Wr   = (const float*)d_in[2];
    const float* att  = (const float*)d_in[3];
    const float* bias = (const float*)d_in[4];
    float* out = (float*)d_out;
    unsigned short* WT = (unsigned short*)d_ws;

    convert_w_kernel<<<512, 256, 0, stream>>>(Wl, Wr, WT);
    if (ws_size >= WS_NEED) {
        unsigned char* xp = (unsigned char*)d_ws + WT_BYTES;
        cvt_x_kernel<<<1024, 512, 0, stream>>>(x, xp);
        gat_main_kernel<<<256, 512, 0, stream>>>(xp, WT, att, bias, out);
    } else {
        gat_fused_legacy<<<1024, 512, 0, stream>>>(x, WT, att, bias, out);
    }
}

// Round 9
// 151.623 us; speedup vs baseline: 3.6589x; 2.2263x over previous
//
#include <hip/hip_runtime.h>
#include <hip/hip_bf16.h>

typedef __attribute__((ext_vector_type(8))) short short8;      // 8 bf16 MFMA operand
typedef __attribute__((ext_vector_type(4))) float f32x4;
typedef __attribute__((ext_vector_type(2))) float f32x2;
typedef __attribute__((ext_vector_type(4))) unsigned short u16x4;

// Block = 8 graphs. Stage: 80 rows x 512 B swizzled bf16 (rows = slot*16 + 2g + parity).
// Phase 3+: partials [8][25][8] f32 (6400 B) + alphas [25][8] f32 (800 B), ALIASED onto
// the stage region (post-GEMM __syncthreads orders the reuse).
#define STAGE_BYTES (80 * 512)                     // 40960 -> 2 blocks/CU by LDS
#define ALPHA_OFF   (8 * 25 * 8 * 4)               // 6400

__device__ __forceinline__ unsigned short f2bf(float f) {
    unsigned int u = __float_as_uint(f);
    unsigned int r = (u + 0x7fffu + ((u >> 16) & 1u)) >> 16;   // RNE
    return (unsigned short)r;
}

// static graph tables (compile-time foldable in unrolled loops)
constexpr int C_SRC[25] = {0,1,0,3,0,5,0,7,1,2,3,4,5,6,7,8, 0,1,2,3,4,5,6,7,8};
constexpr int C_DST[25] = {1,0,3,0,5,0,7,0,2,1,4,3,6,5,8,7, 0,1,2,3,4,5,6,7,8};
constexpr int C_NINC[9]  = {5,3,2,3,2,3,2,3,2};
constexpr int C_IOFF[9]  = {0,5,8,10,13,15,18,20,23};
constexpr int C_INCE[25] = {1,3,5,7,16, 0,9,17, 8,18, 2,11,19, 10,20, 4,13,21, 12,22, 6,15,23, 14,24};
constexpr int C_INCS[25] = {1,3,5,7,0,  0,2,1,  1,2,  0,4,3,  3,4,  0,6,5,  5,6,  0,8,7,  7,8};
// runtime-indexed copies (softmax phase) in global const memory, not scratch
__device__ const int D_NINC[9]  = {5,3,2,3,2,3,2,3,2};
__device__ const int D_IOFF[9]  = {0,5,8,10,13,15,18,20,23};
__device__ const int D_INCE[25] = {1,3,5,7,16, 0,9,17, 8,18, 2,11,19, 10,20, 4,13,21, 12,22, 6,15,23, 14,24};

// WT[n][k] = (n<256 ? W_l[k][n] : W_r[k][n-256]) as bf16 (B-fragments contiguous)
__global__ void convert_w_kernel(const float* __restrict__ Wl,
                                 const float* __restrict__ Wr,
                                 unsigned short* __restrict__ WT) {
    int n = blockIdx.x;      // 0..511
    int k = threadIdx.x;     // 0..255
    float v = (n < 256) ? Wl[k * 256 + n] : Wr[k * 256 + (n - 256)];
    WT[n * 256 + k] = f2bf(v);
}

__global__ __launch_bounds__(512, 4) void gat_fused_kernel(
        const float* __restrict__ x,
        const unsigned short* __restrict__ WT,
        const float* __restrict__ att,
        const float* __restrict__ bias,
        float* __restrict__ out) {
    __shared__ __align__(16) char smem[STAGE_BYTES];
    float* partials = (float*)smem;                // [wave][edge][graph] (aliases stage)
    float* alphas   = (float*)(smem + ALPHA_OFF);  // [edge][graph]       (aliases stage)

    const int tid  = threadIdx.x;
    const int lane = tid & 63;
    const int w    = tid >> 6;        // 8 waves; wave owns cols [32w,32w+32) of L and R
    const int gl   = lane >> 4;       // graph pair 2*gl, 2*gl+1
    const int li   = lane & 15;       // column-within-tile
    const int blk  = blockIdx.x;      // 0..2047, 8 graphs each

    const int c0 = 32 * w + li, c1 = c0 + 16;
    const float attc0 = att[c0], attc1 = att[c1];
    const float bc0   = bias[c0], bc1 = bias[c1];

    // ---- phase 1: stage x -> LDS bf16, rows = (node>>1)*16 + 2g + (node&1), swizzled ----
    const float* xblk = x + (size_t)blk * 18432;   // 8 graphs x 9 nodes x 256
    {
        f32x4 xv[9];
        #pragma unroll
        for (int it = 0; it < 9; ++it)
            xv[it] = *(const f32x4*)(xblk + it * 2048 + tid * 4);
        #pragma unroll
        for (int it = 0; it < 9; ++it) {
            int f    = it * 2048 + tid * 4;
            int gr   = f >> 8;              // g*9 + node, 0..71
            int c    = f & 255;
            int g    = gr / 9;
            int node = gr - g * 9;
            int key  = 2 * g + (node & 1);  // srow & 15
            int srow = ((node >> 1) << 4) + key;
            u16x4 pk = { f2bf(xv[it][0]), f2bf(xv[it][1]), f2bf(xv[it][2]), f2bf(xv[it][3]) };
            *(u16x4*)(smem + srow * 512 + ((2 * c) ^ (key << 4))) = pk;
        }
    }
    __syncthreads();

    const unsigned short* WL = WT + (size_t)(c0 * 256 + gl * 8);
    const unsigned short* WR = WL + 256 * 256;
    const f32x4 ZERO = {0.f, 0.f, 0.f, 0.f};

    // D-frag reg r of tile m: graph 2*gl + (r>>1), node 2*m + (r&1), col = li (+16*nt)
    f32x4 aL[5][2], aR[5][2];

    // ---- phase 2a: L-GEMM (5 m-tiles x 2 n-tiles) ----
    #pragma unroll
    for (int m = 0; m < 5; ++m) { aL[m][0] = ZERO; aL[m][1] = ZERO; }
    #pragma unroll
    for (int kc = 0; kc < 8; ++kc) {
        short8 bl0 = *(const short8*)(WL + kc * 32);
        short8 bl1 = *(const short8*)(WL + 4096 + kc * 32);
        const int inner = ((kc * 64) + (gl * 16)) ^ (li << 4);
        #pragma unroll
        for (int m = 0; m < 5; ++m) {
            short8 a = *(const short8*)(smem + (m * 16 + li) * 512 + inner);
            aL[m][0] = __builtin_amdgcn_mfma_f32_16x16x32_bf16(a, bl0, aL[m][0], 0, 0, 0);
            aL[m][1] = __builtin_amdgcn_mfma_f32_16x16x32_bf16(a, bl1, aL[m][1], 0, 0, 0);
        }
    }
    // ---- phase 2b: R-GEMM ----
    #pragma unroll
    for (int m = 0; m < 5; ++m) { aR[m][0] = ZERO; aR[m][1] = ZERO; }
    #pragma unroll
    for (int kc = 0; kc < 8; ++kc) {
        short8 br0 = *(const short8*)(WR + kc * 32);
        short8 br1 = *(const short8*)(WR + 4096 + kc * 32);
        const int inner = ((kc * 64) + (gl * 16)) ^ (li << 4);
        #pragma unroll
        for (int m = 0; m < 5; ++m) {
            short8 a = *(const short8*)(smem + (m * 16 + li) * 512 + inner);
            aR[m][0] = __builtin_amdgcn_mfma_f32_16x16x32_bf16(a, br0, aR[m][0], 0, 0, 0);
            aR[m][1] = __builtin_amdgcn_mfma_f32_16x16x32_bf16(a, br1, aR[m][1], 0, 0, 0);
        }
    }
    __syncthreads();   // all stage-region reads done; region becomes partials/alphas

    // ---- phase 3: per-edge scores (2 graphs/lane, all nodes in-lane) + 16-lane butterfly ----
    #pragma unroll
    for (int e = 0; e < 25; ++e) {
        const int s = C_SRC[e], d = C_DST[e];
        const int mL = s >> 1, pL = s & 1;
        const int mR = d >> 1, pR = d & 1;
        float p0 = 0.f, p1 = 0.f;
        #pragma unroll
        for (int nt = 0; nt < 2; ++nt) {
            const float ac = nt ? attc1 : attc0;
            float v0 = aL[mL][nt][pL]     + aR[mR][nt][pR];       // graph 2gl
            float v1 = aL[mL][nt][2 + pL] + aR[mR][nt][2 + pR];   // graph 2gl+1
            p0 += ac * fmaxf(v0, 0.2f * v0);
            p1 += ac * fmaxf(v1, 0.2f * v1);
        }
        #pragma unroll
        for (int m = 1; m < 16; m <<= 1) {              // sum over the 16 cols of this wave
            p0 += __shfl_xor(p0, m);
            p1 += __shfl_xor(p1, m);
        }
        if (li == 0) {
            f32x2 pk = {p0, p1};
            *(f32x2*)(partials + (w * 25 + e) * 8 + 2 * gl) = pk;
        }
    }
    __syncthreads();

    // ---- phase 4: segment softmax, one thread per (node, graph) ----
    if (tid < 72) {
        int n = tid >> 3, g = tid & 7;
        int off = D_IOFF[n], cnt = D_NINC[n];
        float mx = -1e30f;
        for (int i = 0; i < cnt; ++i) {
            int e = D_INCE[off + i];
            float s = 0.f;
            #pragma unroll
            for (int ww = 0; ww < 8; ++ww) s += partials[(ww * 25 + e) * 8 + g];
            alphas[e * 8 + g] = s;                      // scratch: raw score
            mx = fmaxf(mx, s);
        }
        float ssum = 0.f;
        for (int i = 0; i < cnt; ++i)
            ssum += __expf(alphas[D_INCE[off + i] * 8 + g] - mx);
        float inv = 1.f / ssum;
        for (int i = 0; i < cnt; ++i) {
            int e = D_INCE[off + i];
            alphas[e * 8 + g] = __expf(alphas[e * 8 + g] - mx) * inv;
        }
    }
    __syncthreads();

    // ---- phase 5: aggregate in registers ----
    #pragma unroll
    for (int n = 0; n < 9; ++n) {
        float o00 = bc0, o01 = bc1;     // graph 2gl
        float o10 = bc0, o11 = bc1;     // graph 2gl+1
        #pragma unroll
        for (int i = 0; i < C_NINC[n]; ++i) {
            const int e  = C_INCE[C_IOFF[n] + i];
            const int sn = C_INCS[C_IOFF[n] + i];
            const int ms = sn >> 1, ps = sn & 1;
            f32x2 al = *(const f32x2*)(alphas + e * 8 + 2 * gl);
            o00 += al[0] * aL[ms][0][ps];
            o01 += al[0] * aL[ms][1][ps];
            o10 += al[1] * aL[ms][0][2 + ps];
            o11 += al[1] * aL[ms][1][2 + ps];
        }
        size_t row0 = ((size_t)blk * 8 + 2 * gl) * 9 + n;
        out[row0 * 256 + c0] = o00;
        out[row0 * 256 + c1] = o01;
        out[(row0 + 9) * 256 + c0] = o10;
        out[(row0 + 9) * 256 + c1] = o11;
    }
}

extern "C" void kernel_launch(void* const* d_in, const int* in_sizes, int n_in,
                              void* d_out, int out_size, void* d_ws, size_t ws_size,
                              hipStream_t stream) {
    const float* x    = (const float*)d_in[0];
    const float* Wl   = (const float*)d_in[1];
    const float* Wr   = (const float*)d_in[2];
    const float* att  = (const float*)d_in[3];
    const float* bias = (const float*)d_in[4];
    float* out = (float*)d_out;
    unsigned short* WT = (unsigned short*)d_ws;      // 512*256 bf16 = 256 KB

    convert_w_kernel<<<512, 256, 0, stream>>>(Wl, Wr, WT);
    gat_fused_kernel<<<2048, 512, 0, stream>>>(x, WT, att, bias, out);
}

// Round 10
// 148.668 us; speedup vs baseline: 3.7316x; 1.0199x over previous
//
#include <hip/hip_runtime.h>
#include <hip/hip_bf16.h>

typedef __attribute__((ext_vector_type(8))) short short8;      // 8 bf16 MFMA operand
typedef __attribute__((ext_vector_type(4))) float f32x4;
typedef __attribute__((ext_vector_type(2))) float f32x2;
typedef __attribute__((ext_vector_type(4))) unsigned short u16x4;

// Block = 8 graphs. Stage: 80 rows x 512 B swizzled bf16 (row = (node>>1)*16 + 2g + (node&1)).
// partials and alphas live in SEPARATE LDS (no aliasing, no extra barrier).
#define STAGE_BYTES (80 * 512)                     // 40960
#define PART_OFF    STAGE_BYTES                    // [16][25][8] f32 = 12800
#define ALPHA_OFF   (PART_OFF + 16 * 25 * 8 * 4)   // 53760: [25][8] f32 = 800
#define LDS_BYTES   (ALPHA_OFF + 25 * 8 * 4)       // 54560 -> 2 blocks/CU by LDS

__device__ __forceinline__ unsigned short f2bf(float f) {
    unsigned int u = __float_as_uint(f);
    unsigned int r = (u + 0x7fffu + ((u >> 16) & 1u)) >> 16;   // RNE
    return (unsigned short)r;
}

// 16-lane sum via DPP on the VALU pipe (no DS ops). xor-basis {1,2,7,15}:
// quad_perm[1,0,3,2]=0xB1, quad_perm[2,3,0,1]=0x4E, row_half_mirror=0x141, row_mirror=0x140.
template<int CTRL>
__device__ __forceinline__ float dpp_add(float v) {
    int p = __builtin_amdgcn_update_dpp(0, __float_as_int(v), CTRL, 0xf, 0xf, true);
    return v + __int_as_float(p);
}
__device__ __forceinline__ float sum16(float v) {
    v = dpp_add<0xB1>(v);
    v = dpp_add<0x4E>(v);
    v = dpp_add<0x141>(v);
    v = dpp_add<0x140>(v);
    return v;
}

// static graph tables (compile-time foldable in unrolled loops)
constexpr int C_SRC[25] = {0,1,0,3,0,5,0,7,1,2,3,4,5,6,7,8, 0,1,2,3,4,5,6,7,8};
constexpr int C_DST[25] = {1,0,3,0,5,0,7,0,2,1,4,3,6,5,8,7, 0,1,2,3,4,5,6,7,8};
constexpr int C_NINC[9]  = {5,3,2,3,2,3,2,3,2};
constexpr int C_IOFF[9]  = {0,5,8,10,13,15,18,20,23};
constexpr int C_INCE[25] = {1,3,5,7,16, 0,9,17, 8,18, 2,11,19, 10,20, 4,13,21, 12,22, 6,15,23, 14,24};
constexpr int C_INCS[25] = {1,3,5,7,0,  0,2,1,  1,2,  0,4,3,  3,4,  0,6,5,  5,6,  0,8,7,  7,8};
// runtime-indexed copies (softmax phase) in global const memory, not scratch
__device__ const int D_NINC[9]  = {5,3,2,3,2,3,2,3,2};
__device__ const int D_IOFF[9]  = {0,5,8,10,13,15,18,20,23};
__device__ const int D_INCE[25] = {1,3,5,7,16, 0,9,17, 8,18, 2,11,19, 10,20, 4,13,21, 12,22, 6,15,23, 14,24};

// per-edge partial scores for one n-tile: fold aRt into scores, then aRt dies.
template<int NT>
__device__ __forceinline__ void edge_scores(const f32x4 (&aL)[5][2], const f32x4 (&aRt)[5],
                                            float ac, float* pbase, int li) {
    #pragma unroll
    for (int e = 0; e < 25; ++e) {
        const int s = C_SRC[e], d = C_DST[e];
        const int mL = s >> 1, pL = s & 1;
        const int mR = d >> 1, pR = d & 1;
        float v0 = aL[mL][NT][pL]     + aRt[mR][pR];       // graph 2gl
        float v1 = aL[mL][NT][2 + pL] + aRt[mR][2 + pR];   // graph 2gl+1
        float p0 = ac * fmaxf(v0, 0.2f * v0);
        float p1 = ac * fmaxf(v1, 0.2f * v1);
        p0 = sum16(p0);
        p1 = sum16(p1);
        if (li == 0) {
            f32x2 pk = {p0, p1};
            *(f32x2*)(pbase + e * 8) = pk;
        }
    }
}

// WT[n][k] = (n<256 ? W_l[k][n] : W_r[k][n-256]) as bf16 (B-fragments contiguous)
__global__ void convert_w_kernel(const float* __restrict__ Wl,
                                 const float* __restrict__ Wr,
                                 unsigned short* __restrict__ WT) {
    int n = blockIdx.x;      // 0..511
    int k = threadIdx.x;     // 0..255
    float v = (n < 256) ? Wl[k * 256 + n] : Wr[k * 256 + (n - 256)];
    WT[n * 256 + k] = f2bf(v);
}

__global__ __launch_bounds__(512, 4) void gat_fused_kernel(
        const float* __restrict__ x,
        const unsigned short* __restrict__ WT,
        const float* __restrict__ att,
        const float* __restrict__ bias,
        float* __restrict__ out) {
    __shared__ __align__(16) char smem[LDS_BYTES];
    float* partials = (float*)(smem + PART_OFF);   // [(w*2+nt)][edge][graph]
    float* alphas   = (float*)(smem + ALPHA_OFF);  // [edge][graph]

    const int tid  = threadIdx.x;
    const int lane = tid & 63;
    const int w    = tid >> 6;        // 8 waves; wave owns cols [32w,32w+32) of L and R
    const int gl   = lane >> 4;       // graph pair 2*gl, 2*gl+1
    const int li   = lane & 15;       // column-within-tile
    const int blk  = blockIdx.x;      // 0..2047, 8 graphs each

    const int c0 = 32 * w + li, c1 = c0 + 16;
    const float attc0 = att[c0], attc1 = att[c1];
    const float bc0   = bias[c0], bc1 = bias[c1];

    // ---- phase 1: stage x -> LDS bf16, rows = (node>>1)*16 + 2g + (node&1), swizzled ----
    const float* xblk = x + (size_t)blk * 18432;   // 8 graphs x 9 nodes x 256
    {
        f32x4 xv[9];
        #pragma unroll
        for (int it = 0; it < 9; ++it)
            xv[it] = *(const f32x4*)(xblk + it * 2048 + tid * 4);
        #pragma unroll
        for (int it = 0; it < 9; ++it) {
            int f    = it * 2048 + tid * 4;
            int gr   = f >> 8;              // g*9 + node, 0..71
            int c    = f & 255;
            int g    = gr / 9;
            int node = gr - g * 9;
            int key  = 2 * g + (node & 1);  // srow & 15
            int srow = ((node >> 1) << 4) + key;
            u16x4 pk = { f2bf(xv[it][0]), f2bf(xv[it][1]), f2bf(xv[it][2]), f2bf(xv[it][3]) };
            *(u16x4*)(smem + srow * 512 + ((2 * c) ^ (key << 4))) = pk;
        }
    }
    __syncthreads();

    const unsigned short* WL = WT + (size_t)(c0 * 256 + gl * 8);
    const unsigned short* WR = WL + 256 * 256;
    const f32x4 ZERO = {0.f, 0.f, 0.f, 0.f};

    // D-frag reg r of tile m: graph 2*gl + (r>>1), node 2*m + (r&1), col = li (+16*nt)
    f32x4 aL[5][2];
    #pragma unroll
    for (int m = 0; m < 5; ++m) { aL[m][0] = ZERO; aL[m][1] = ZERO; }

    // ---- pass 1: aL (both n-tiles) + aR n-tile 0; fold scores nt0 ----
    {
        f32x4 aRt[5];
        #pragma unroll
        for (int m = 0; m < 5; ++m) aRt[m] = ZERO;
        #pragma unroll
        for (int kc = 0; kc < 8; ++kc) {
            short8 bl0 = *(const short8*)(WL + kc * 32);
            short8 bl1 = *(const short8*)(WL + 4096 + kc * 32);
            short8 br0 = *(const short8*)(WR + kc * 32);
            const int inner = ((kc * 64) + (gl * 16)) ^ (li << 4);
            #pragma unroll
            for (int m = 0; m < 5; ++m) {
                short8 a = *(const short8*)(smem + (m * 16 + li) * 512 + inner);
                aL[m][0] = __builtin_amdgcn_mfma_f32_16x16x32_bf16(a, bl0, aL[m][0], 0, 0, 0);
                aL[m][1] = __builtin_amdgcn_mfma_f32_16x16x32_bf16(a, bl1, aL[m][1], 0, 0, 0);
                aRt[m]   = __builtin_amdgcn_mfma_f32_16x16x32_bf16(a, br0, aRt[m],   0, 0, 0);
            }
        }
        edge_scores<0>(aL, aRt, attc0, partials + (w * 2 + 0) * 200 + 2 * gl, li);
    }

    // ---- pass 2: aR n-tile 1; fold scores nt1 ----
    {
        f32x4 aRt[5];
        #pragma unroll
        for (int m = 0; m < 5; ++m) aRt[m] = ZERO;
        #pragma unroll
        for (int kc = 0; kc < 8; ++kc) {
            short8 br1 = *(const short8*)(WR + 4096 + kc * 32);
            const int inner = ((kc * 64) + (gl * 16)) ^ (li << 4);
            #pragma unroll
            for (int m = 0; m < 5; ++m) {
                short8 a = *(const short8*)(smem + (m * 16 + li) * 512 + inner);
                aRt[m] = __builtin_amdgcn_mfma_f32_16x16x32_bf16(a, br1, aRt[m], 0, 0, 0);
            }
        }
        edge_scores<1>(aL, aRt, attc1, partials + (w * 2 + 1) * 200 + 2 * gl, li);
    }
    __syncthreads();   // partials ready

    // ---- segment softmax, one thread per (node, graph): sum 16 partial slots ----
    if (tid < 72) {
        int n = tid >> 3, g = tid & 7;
        int off = D_IOFF[n], cnt = D_NINC[n];
        float mx = -1e30f;
        for (int i = 0; i < cnt; ++i) {
            int e = D_INCE[off + i];
            float s = 0.f;
            #pragma unroll
            for (int ww = 0; ww < 16; ++ww) s += partials[ww * 200 + e * 8 + g];
            alphas[e * 8 + g] = s;                      // scratch: raw score
            mx = fmaxf(mx, s);
        }
        float ssum = 0.f;
        for (int i = 0; i < cnt; ++i)
            ssum += __expf(alphas[D_INCE[off + i] * 8 + g] - mx);
        float inv = 1.f / ssum;
        for (int i = 0; i < cnt; ++i) {
            int e = D_INCE[off + i];
            alphas[e * 8 + g] = __expf(alphas[e * 8 + g] - mx) * inv;
        }
    }
    __syncthreads();

    // ---- aggregate in registers (needs only aL + alphas) ----
    #pragma unroll
    for (int n = 0; n < 9; ++n) {
        float o00 = bc0, o01 = bc1;     // graph 2gl
        float o10 = bc0, o11 = bc1;     // graph 2gl+1
        #pragma unroll
        for (int i = 0; i < C_NINC[n]; ++i) {
            const int e  = C_INCE[C_IOFF[n] + i];
            const int sn = C_INCS[C_IOFF[n] + i];
            const int ms = sn >> 1, ps = sn & 1;
            f32x2 al = *(const f32x2*)(alphas + e * 8 + 2 * gl);
            o00 += al[0] * aL[ms][0][ps];
            o01 += al[0] * aL[ms][1][ps];
            o10 += al[1] * aL[ms][0][2 + ps];
            o11 += al[1] * aL[ms][1][2 + ps];
        }
        size_t row0 = ((size_t)blk * 8 + 2 * gl) * 9 + n;
        out[row0 * 256 + c0] = o00;
        out[row0 * 256 + c1] = o01;
        out[(row0 + 9) * 256 + c0] = o10;
        out[(row0 + 9) * 256 + c1] = o11;
    }
}

extern "C" void kernel_launch(void* const* d_in, const int* in_sizes, int n_in,
                              void* d_out, int out_size, void* d_ws, size_t ws_size,
                              hipStream_t stream) {
    const float* x    = (const float*)d_in[0];
    const float* Wl   = (const float*)d_in[1];
    const float* Wr   = (const float*)d_in[2];
    const float* att  = (const float*)d_in[3];
    const float* bias = (const float*)d_in[4];
    float* out = (float*)d_out;
    unsigned short* WT = (unsigned short*)d_ws;      // 512*256 bf16 = 256 KB

    convert_w_kernel<<<512, 256, 0, stream>>>(Wl, Wr, WT);
    gat_fused_kernel<<<2048, 512, 0, stream>>>(x, WT, att, bias, out);
}